// Round 2
// baseline (3079.226 us; speedup 1.0000x reference)
//
#include <hip/hip_runtime.h>
#include <hip/hip_bf16.h>

#define IN_SIZE 256
#define N_NODES 1024
#define DEG 32
#define BATCH 16384
#define OUT_SIZE 16
#define N_ROWS (IN_SIZE + N_NODES)      // 1280 rows
#define ROW_STRIDE (BATCH + 16)         // elems; +pad breaks power-of-2 L2 set aliasing

__device__ inline float toF(float v) { return v; }
__device__ inline float toF(__hip_bfloat16 v) { return __bfloat162float(v); }
__device__ inline void fromF(float& d, float v) { d = v; }
__device__ inline void fromF(__hip_bfloat16& d, float v) { d = __float2bfloat16(v); }

// ---------------------------------------------------------------------------
// Runtime dtype detector. Decode EVEN-index elements of x as bf16:
//  - true bf16 N(0,1) data: ~99.9% of |v| in [1e-3, 1e3]
//  - fp32-stored data: even bf16 elements are fp32 low-mantissa halves ->
//    pseudo-random exponent -> only ~8% plausible.
// flag = 1 (bf16) iff >= 90% plausible.
// ---------------------------------------------------------------------------
__global__ __launch_bounds__(64) void ne_detect(const void* __restrict__ xraw,
                                                int* __restrict__ flag) {
    const __hip_bfloat16* xb = (const __hip_bfloat16*)xraw;
    const int tid = threadIdx.x;                 // 0..63
    int plausible = 0;
    for (int k = tid; k < 2048; k += 64) {       // even elements 0..4094 (in-bounds either way)
        const float v = __bfloat162float(xb[2 * k]);
        const float a = fabsf(v);
        plausible += (a == 0.0f) || (a > 1e-3f && a < 1e3f) ? 1 : 0;
    }
    for (int off = 32; off > 0; off >>= 1) plausible += __shfl_down(plausible, off);
    if (tid == 0) *flag = (plausible >= (2048 * 9) / 10) ? 1 : 0;
}

// ---------------------------------------------------------------------------
// Transpose x [BATCH][IN_SIZE] -> activs rows 0..IN_SIZE-1 as [row][batch].
// ---------------------------------------------------------------------------
template <typename ActT>
__global__ __launch_bounds__(1024) void ne_transpose(const void* __restrict__ xraw,
                                                     ActT* __restrict__ activs,
                                                     const int* __restrict__ flag) {
    const int isbf16 = *flag;                    // uniform
    __shared__ float tile[64][65];
    const int tx = threadIdx.x;                  // 0..63
    const int ty = threadIdx.y;                  // 0..15
    const int p0 = blockIdx.x * 64;
    const int b0 = blockIdx.y * 64;
    const float* xf = (const float*)xraw;
    const __hip_bfloat16* xb = (const __hip_bfloat16*)xraw;

#pragma unroll
    for (int r = 0; r < 4; ++r) {
        const int b = b0 + ty + 16 * r;
        const size_t off = (size_t)b * IN_SIZE + p0 + tx;
        tile[ty + 16 * r][tx] = isbf16 ? __bfloat162float(xb[off]) : xf[off];
    }
    __syncthreads();
#pragma unroll
    for (int r = 0; r < 4; ++r) {
        const int p = p0 + ty + 16 * r;
        fromF(activs[(size_t)p * ROW_STRIDE + b0 + tx], tile[tx][ty + 16 * r]);
    }
}

// ---------------------------------------------------------------------------
// Sequential network. One thread owns one batch column; zero synchronization.
// idx/w loads are wave-uniform (scalar); gathers are coalesced 256B wave loads.
// ---------------------------------------------------------------------------
template <typename ActT>
__global__ __launch_bounds__(64) void ne_forward(const void* __restrict__ wraw,
                                                 const int* __restrict__ in_idxs,
                                                 ActT* __restrict__ activs,
                                                 void* __restrict__ outraw,
                                                 const int* __restrict__ flag) {
    const int isbf16 = *flag;                    // uniform
    const int col = blockIdx.x * 64 + threadIdx.x;
    ActT* __restrict__ acol = activs + col;
    const float* wf = (const float*)wraw;
    const __hip_bfloat16* wb = (const __hip_bfloat16*)wraw;
    float* outf = (float*)outraw;
    __hip_bfloat16* outb = (__hip_bfloat16*)outraw;

    for (int i = 0; i < N_NODES; ++i) {
        const int* __restrict__ idx = in_idxs + i * DEG;
        float acc = 0.0f;
#pragma unroll
        for (int d = 0; d < DEG; ++d) {
            int j = idx[d];
            j = j < 0 ? 0 : (j >= N_ROWS ? N_ROWS - 1 : j);          // safety clamp (scalar)
            const float a = toF(acol[(size_t)j * ROW_STRIDE]);
            const float w = isbf16 ? __bfloat162float(wb[i * DEG + d]) : wf[i * DEG + d];
            acc += a * w;
        }
        // overflow-free tanh: s=e^{-2|a|} in (0,1]; t=sign(a)*(1-s)/(1+s)
        const float s = __expf(-2.0f * fabsf(acc));
        const float t = copysignf((1.0f - s) / (1.0f + s), acc);

        fromF(acol[(size_t)(IN_SIZE + i) * ROW_STRIDE], t);

        if (i >= N_NODES - OUT_SIZE) {
            const size_t o = (size_t)(i - (N_NODES - OUT_SIZE)) * BATCH + col;
            if (isbf16) outb[o] = __float2bfloat16(t);
            else        outf[o] = t;
        }
    }
}

extern "C" void kernel_launch(void* const* d_in, const int* in_sizes, int n_in,
                              void* d_out, int out_size, void* d_ws, size_t ws_size,
                              hipStream_t stream) {
    const void* x    = d_in[0];                  // [BATCH][IN_SIZE]
    const void* w    = d_in[1];                  // [N_NODES][DEG]
    const int* idxs  = (const int*)d_in[2];      // [N_NODES][DEG]
    int* flag        = (int*)((char*)d_ws + (ws_size - 16));

    ne_detect<<<1, 64, 0, stream>>>(x, flag);

    const size_t needF32 = (size_t)N_ROWS * ROW_STRIDE * sizeof(float) + 64;
    if (ws_size >= needF32) {                    // ws_size constant across calls -> capture-safe
        float* activs = (float*)d_ws;
        ne_transpose<float><<<dim3(IN_SIZE / 64, BATCH / 64), dim3(64, 16), 0, stream>>>(x, activs, flag);
        ne_forward<float><<<dim3(BATCH / 64), dim3(64), 0, stream>>>(w, idxs, activs, d_out, flag);
    } else {                                     // compact fallback: bf16 activations (42 MB)
        __hip_bfloat16* activs = (__hip_bfloat16*)d_ws;
        ne_transpose<__hip_bfloat16><<<dim3(IN_SIZE / 64, BATCH / 64), dim3(64, 16), 0, stream>>>(x, activs, flag);
        ne_forward<__hip_bfloat16><<<dim3(BATCH / 64), dim3(64), 0, stream>>>(w, idxs, activs, d_out, flag);
    }
}

// Round 3
// 596.529 us; speedup vs baseline: 5.1619x; 5.1619x over previous
//
#include <hip/hip_runtime.h>
#include <hip/hip_bf16.h>

#define IN_SIZE 256
#define N_NODES 1024
#define DEG 32
#define BATCH 16384
#define OUT_SIZE 16
#define N_ROWS (IN_SIZE + N_NODES)   // 1280 activation rows
#define COLS 8                        // batch columns per (single-wave) block

// ---------------------------------------------------------------------------
// Runtime dtype detector (unchanged from the passing round). Decodes EVEN
// elements of x as bf16; fp32-stored data yields implausible exponents.
// ---------------------------------------------------------------------------
__global__ __launch_bounds__(64) void ne_detect(const void* __restrict__ xraw,
                                                int* __restrict__ flag) {
    const unsigned short* xb = (const unsigned short*)xraw;
    const int tid = threadIdx.x;
    int plausible = 0;
    for (int k = tid; k < 2048; k += 64) {
        const float v = __uint_as_float((unsigned)xb[2 * k] << 16);
        const float a = fabsf(v);
        plausible += (a == 0.0f) || (a > 1e-3f && a < 1e3f) ? 1 : 0;
    }
    for (int off = 32; off > 0; off >>= 1) plausible += __shfl_down(plausible, off);
    if (tid == 0) *flag = (plausible >= (2048 * 9) / 10) ? 1 : 0;
}

// ---------------------------------------------------------------------------
// Convert x and weights to fp32 in ws so the hot loop is branch-free.
// ---------------------------------------------------------------------------
__global__ __launch_bounds__(256) void ne_prep(const void* __restrict__ xraw,
                                               const void* __restrict__ wraw,
                                               float* __restrict__ xf,
                                               float* __restrict__ wf,
                                               const int* __restrict__ flag) {
    const int isbf16 = *flag;                    // uniform
    const int n_x = BATCH * IN_SIZE;
    const int n_w = N_NODES * DEG;
    const int tid = blockIdx.x * 256 + threadIdx.x;
    const int stride = gridDim.x * 256;
    if (isbf16) {
        const unsigned short* xb = (const unsigned short*)xraw;
        const unsigned short* wb = (const unsigned short*)wraw;
        for (int k = tid; k < n_x; k += stride) xf[k] = __uint_as_float((unsigned)xb[k] << 16);
        for (int k = tid; k < n_w; k += stride) wf[k] = __uint_as_float((unsigned)wb[k] << 16);
    } else {
        const float* xs = (const float*)xraw;
        const float* ws = (const float*)wraw;
        for (int k = tid; k < n_x; k += stride) xf[k] = xs[k];
        for (int k = tid; k < n_w; k += stride) wf[k] = ws[k];
    }
}

// ---------------------------------------------------------------------------
// LDS-resident sequential network. One wave per block owns COLS=8 batch
// columns; the full 1280-row activation history lives in LDS (40 KB -> 4
// blocks/CU). Lane = (d-group q 0..7) x (col c 0..7): 4 gathers/lane, then
// 3x shfl_xor reduce. Single wave => DS ops in-order => ZERO barriers.
// idx/weights prefetched one node ahead (L2-hot int4/float4 loads).
// ---------------------------------------------------------------------------
__global__ __launch_bounds__(64) void ne_forward(const float* __restrict__ xf,
                                                 const float* __restrict__ wf,
                                                 const int* __restrict__ in_idxs,
                                                 void* __restrict__ outraw,
                                                 const int* __restrict__ flag) {
    extern __shared__ float act[];               // [N_ROWS][COLS]
    const int lane = threadIdx.x;
    const int c = lane & (COLS - 1);             // column within block
    const int q = lane >> 3;                     // d-group 0..7
    const int c0 = blockIdx.x * COLS;            // global column base

    // ---- seed rows 0..IN_SIZE-1 from x (row-major fp32) ----
    {
        const int b = lane >> 3;                 // local batch row 0..7
        const int seg = lane & 7;                // 32-element segment 0..7
#pragma unroll
        for (int t4 = 0; t4 < 8; ++t4) {
            const int p = seg * 32 + t4 * 4;
            const float4 v = *(const float4*)(xf + (size_t)(c0 + b) * IN_SIZE + p);
            act[(p + 0) * COLS + b] = v.x;
            act[(p + 1) * COLS + b] = v.y;
            act[(p + 2) * COLS + b] = v.z;
            act[(p + 3) * COLS + b] = v.w;
        }
    }
    // single wave: LDS pipeline processes this wave's DS ops in order -> no barrier

    const int isbf16 = *flag;                    // uniform
    float* outf = (float*)outraw;
    unsigned short* outb = (unsigned short*)outraw;

    int4 nid  = *(const int4*)(in_idxs + q * 4);
    float4 nw = *(const float4*)(wf + q * 4);

    for (int i = 0; i < N_NODES; ++i) {
        const int4 id = nid;
        const float4 wv = nw;
        const int inext = (i + 1 < N_NODES) ? i + 1 : N_NODES - 1;   // clamped prefetch
        nid = *(const int4*)(in_idxs + (size_t)inext * DEG + q * 4);
        nw  = *(const float4*)(wf + (size_t)inext * DEG + q * 4);

        float acc =      act[id.x * COLS + c] * wv.x;
        acc = fmaf(act[id.y * COLS + c], wv.y, acc);
        acc = fmaf(act[id.z * COLS + c], wv.z, acc);
        acc = fmaf(act[id.w * COLS + c], wv.w, acc);

        acc += __shfl_xor(acc, 8);
        acc += __shfl_xor(acc, 16);
        acc += __shfl_xor(acc, 32);              // full dot in every lane

        // overflow-free tanh: s = e^{-2|a|}, t = sign(a) * (1-s)/(1+s)
        const float s = __expf(-2.0f * fabsf(acc));
        const float t = copysignf((1.0f - s) * __builtin_amdgcn_rcpf(1.0f + s), acc);

        if (q == 0) {
            act[(IN_SIZE + i) * COLS + c] = t;
            if (i >= N_NODES - OUT_SIZE) {
                const size_t o = (size_t)(i - (N_NODES - OUT_SIZE)) * BATCH + c0 + c;
                if (isbf16) {
                    const unsigned u = __float_as_uint(t);
                    outb[o] = (unsigned short)((u + 0x7FFFu + ((u >> 16) & 1u)) >> 16); // RNE
                } else {
                    outf[o] = t;
                }
            }
        }
    }
}

extern "C" void kernel_launch(void* const* d_in, const int* in_sizes, int n_in,
                              void* d_out, int out_size, void* d_ws, size_t ws_size,
                              hipStream_t stream) {
    const void* x   = d_in[0];                   // [BATCH][IN_SIZE]
    const void* w   = d_in[1];                   // [N_NODES][DEG]
    const int* idxs = (const int*)d_in[2];       // [N_NODES][DEG]

    float* xf = (float*)d_ws;                                        // 16 MB
    float* wf = (float*)((char*)d_ws + (size_t)BATCH * IN_SIZE * 4); // 128 KB
    int* flag = (int*)((char*)d_ws + ((ws_size - 16) & ~(size_t)15));

    ne_detect<<<1, 64, 0, stream>>>(x, flag);
    ne_prep<<<512, 256, 0, stream>>>(x, w, xf, wf, flag);

    // 2048 single-wave blocks, 40 KB LDS each -> 4 blocks/CU, no barriers
    ne_forward<<<dim3(BATCH / COLS), dim3(64), N_ROWS * COLS * sizeof(float), stream>>>(
        xf, wf, idxs, d_out, flag);
}